// Round 2
// baseline (414.413 us; speedup 1.0000x reference)
//
#include <hip/hip_runtime.h>
#include <math.h>

// GaussianLayer: per row (B=524288): mu=x[0], sigma=exp(0.5*x[1]);
// pdf over xx=-99..99, cumsum over 199 bins. Output (B,199) fp32 = 417 MB.
//
// Accounting: dur_us includes the harness's ~266 us / 1.67 GB output
// re-poison fill each iteration. Kernel-proper ~143 us vs 67 us write
// roofline at the fill's own 6.26 TB/s.
//
// R7 POST-MORTEM: sc0 sc1 nt L2-bypass stores -> NaN. Harness poison fill
// leaves dirty lines in L2; they evict AFTER our HBM-direct writes and
// clobber them. Write-around is unsafe here. Also: the fill itself writes
// at 6.26 TB/s with FETCH~0 using plain contiguous dwordx4 stores ->
// write-allocate-fetch (World A) never was the problem.
//
// R8 (World B, structural): 16384 one-shot blocks are ~85% stalled
// (cold x load + 2 full __syncthreads vmcnt(0) drains + endpgm per 25 KB
// written). -> Persistent pipelined blocks: grid=1536 (6/CU), grid-stride
// over row-groups; raw s_barrier with lgkmcnt(0)-ONLY waits so store
// traffic from iteration k drains under compute of k+1; next x prefetched
// before the store burst (counted vmcnt wait, not a drain).
// Cross-iteration LDS safety: each wave's sweep reads complete (lgkmcnt
// before store issue) before it can arrive at next iteration's barrier-1;
// c-writes happen only after that barrier -> no wave can overwrite LDS
// another wave is still reading. tot[] analogous via barrier-2.

#define ROWS 32
#define SEG  25     // bins per segment; 8 segments, last has 24
#define NB   199
#define NT   256
#define GRID 1536   // 256 CU x 6 blocks/CU (LDS-limited occupancy)

typedef float fx4 __attribute__((ext_vector_type(4)));

__device__ __forceinline__ void sync_lds_only() {
    // barrier WITHOUT vmcnt drain: LDS ops ordered, global stores left in flight.
    // asm memory clobber = optimizer fence; sched_barrier pins post-RA motion
    // (rule #18: MI scheduler can otherwise hoist ds ops across s_barrier).
    asm volatile("s_waitcnt lgkmcnt(0)" ::: "memory");
    __builtin_amdgcn_s_barrier();
    __builtin_amdgcn_sched_barrier(0);
}

__global__ __launch_bounds__(NT, 6)
void gauss_cdf_kernel(const float2* __restrict__ x, float* __restrict__ out, int B) {
    __shared__ __align__(16) float lds[ROWS * NB];   // 25,472 B, flat == out layout
    __shared__ float tot[8 * ROWS];                  // per-segment totals [seg][row]

    const int tid = threadIdx.x;
    const int r   = tid & 31;        // row within group
    const int q   = tid >> 5;        // segment index 0..7
    const int nG  = (B + ROWS - 1) / ROWS;   // 16384 row-groups

    const int qs   = q * SEG;
    const int qlen = (q == 7) ? 24 : 25;     // bin 199 doesn't exist

    int g = blockIdx.x;
    float2 v = make_float2(0.f, 0.f);
    if (g < nG) {                            // prologue load for first group
        int row = g * ROWS + r;
        v = x[row < B ? row : 0];
    }

    for (; g < nG; g += GRID) {
        const int rowBase = g * ROWS;

        const float mu = v.x;
        const float s  = __expf(-0.5f * v.y);            // 1/sigma
        const float inv_norm = 0.3989422804014327f * s;  // 1/(sigma*sqrt(2pi))
        const float coefA2   = -0.7213475204444817f * s * s; // -log2e/(2 sigma^2)

        const float tb = (float)(qs - 99) - mu;

        // segment cumsum in registers (fully unrolled -> static indices)
        float c[SEG];
        float acc = 0.f;
        #pragma unroll
        for (int j = 0; j < SEG; ++j) {
            float t = tb + (float)j;
            acc += inv_norm * __builtin_amdgcn_exp2f(coefA2 * t * t);
            c[j] = acc;
        }
        tot[q * ROWS + r] = acc;   // q=7's extra bin harmless: tot[7] never read
        sync_lds_only();           // barrier 1

        // prefix of earlier segments' totals (<=7 LDS reads, 2-way alias free)
        float base = 0.f;
        #pragma unroll
        for (int k = 0; k < 7; ++k)
            if (k < q) base += tot[k * ROWS + r];

        float* dst = lds + r * NB + qs;
        #pragma unroll
        for (int j = 0; j < SEG; ++j)
            if (j < qlen) dst[j] = c[j] + base;
        sync_lds_only();           // barrier 2

        // prefetch next group's x BEFORE the store burst: its consumer-wait
        // becomes a counted vmcnt, not a full drain of the burst.
        {
            int gn = g + GRID;
            if (gn < nG) {
                int rown = gn * ROWS + r;
                v = x[rown < B ? rown : 0];
            }
        }

        // contiguous sweep: group region = 25,472 B = 199 x 128B whole lines.
        // Prefetch LDS slices to registers (one lgkm drain), burst nt stores.
        if (rowBase + ROWS <= B) {
            const fx4* src = reinterpret_cast<const fx4*>(lds);
            fx4* d4 = reinterpret_cast<fx4*>(out + (size_t)rowBase * NB);
            // ROWS*NB/4 = 1592 float4s; 6 per thread + 7th for tid<56
            fx4 v0 = src[tid];
            fx4 v1 = src[tid + 256];
            fx4 v2 = src[tid + 512];
            fx4 v3 = src[tid + 768];
            fx4 v4 = src[tid + 1024];
            fx4 v5 = src[tid + 1280];
            fx4 v6;
            const bool has7 = tid < (ROWS * NB / 4 - 6 * 256);   // tid < 56
            if (has7) v6 = src[tid + 1536];
            __builtin_nontemporal_store(v0, &d4[tid]);
            __builtin_nontemporal_store(v1, &d4[tid + 256]);
            __builtin_nontemporal_store(v2, &d4[tid + 512]);
            __builtin_nontemporal_store(v3, &d4[tid + 768]);
            __builtin_nontemporal_store(v4, &d4[tid + 1024]);
            __builtin_nontemporal_store(v5, &d4[tid + 1280]);
            if (has7) __builtin_nontemporal_store(v6, &d4[tid + 1536]);
        } else {  // generic tail (unused for B=524288)
            for (int i = tid; i < ROWS * NB; i += NT) {
                int rr = i / NB;
                if (rowBase + rr < B)
                    __builtin_nontemporal_store(lds[i], &out[(size_t)rowBase * NB + i]);
            }
        }
        // loop: compute of group g+GRID proceeds while this burst drains.
    }
}

extern "C" void kernel_launch(void* const* d_in, const int* in_sizes, int n_in,
                              void* d_out, int out_size, void* d_ws, size_t ws_size,
                              hipStream_t stream) {
    const float2* x = (const float2*)d_in[0];
    float* out = (float*)d_out;
    const int B = in_sizes[0] / 2;                  // (B,2) fp32
    gauss_cdf_kernel<<<GRID, NT, 0, stream>>>(x, out, B);
}